// Round 3
// baseline (146.534 us; speedup 1.0000x reference)
//
#include <hip/hip_runtime.h>
#include <hip/hip_bf16.h>

#define BATCH 8
#define NN    256
#define FIN   128
#define H1    4
#define C1    128
#define HC1   512   // H1*C1
#define NEG_SLOPE 0.2f

__device__ __forceinline__ float lrelu(float v) {
    return v > 0.f ? v : NEG_SLOPE * v;
}

// ---------------- K1: h1 = x @ W1, fused a_src1/a_dst1 ----------------------
// grid (64, 8), block 512. Block: 4 rows x 512 cols (all cols -> full a-reduce).
__global__ __launch_bounds__(512, 4)
void gemm1_fused(const float* __restrict__ x, const float* __restrict__ W1,
                 const float* __restrict__ as1, const float* __restrict__ ad1,
                 float* __restrict__ h1, float* __restrict__ a_src,
                 float* __restrict__ a_dst) {
    __shared__ float xs[4][FIN];
    __shared__ float redS[4][8], redD[4][8];
    const int b = blockIdx.y, r0 = blockIdx.x * 4, t = threadIdx.x;

    xs[t >> 7][t & 127] = x[(b * NN + r0) * FIN + t];   // 4 rows x 128, coalesced
    __syncthreads();

    float a0 = 0.f, a1 = 0.f, a2 = 0.f, a3 = 0.f;
    #pragma unroll 8
    for (int k = 0; k < FIN; ++k) {
        float w = W1[k * HC1 + t];
        a0 = fmaf(xs[0][k], w, a0);
        a1 = fmaf(xs[1][k], w, a1);
        a2 = fmaf(xs[2][k], w, a2);
        a3 = fmaf(xs[3][k], w, a3);
    }
    float acc[4] = {a0, a1, a2, a3};
    #pragma unroll
    for (int r = 0; r < 4; ++r)
        h1[(b * NN + r0 + r) * HC1 + t] = acc[r];

    // fused a-reductions: col t -> head t>>7; att vectors are flat [512].
    const float as = as1[t], ad = ad1[t];
    const int w = t >> 6, lane = t & 63;
    #pragma unroll
    for (int r = 0; r < 4; ++r) {
        float s = acc[r] * as, d = acc[r] * ad;
        #pragma unroll
        for (int off = 32; off > 0; off >>= 1) {
            s += __shfl_down(s, off, 64);
            d += __shfl_down(d, off, 64);
        }
        if (lane == 0) { redS[r][w] = s; redD[r][w] = d; }
    }
    __syncthreads();
    if (t < 16) {   // wave w covers cols [64w,64w+63] -> head w>>1
        int r = t & 3, h = t >> 2;
        a_src[(b * NN + r0 + r) * H1 + h] = redS[r][2 * h] + redS[r][2 * h + 1];
        a_dst[(b * NN + r0 + r) * H1 + h] = redD[r][2 * h] + redD[r][2 * h + 1];
    }
}

// ---------------- K2: layer-1 softmax + aggregate + bias + relu -------------
// grid (16 dst-tiles, 4 heads, 8 batch), block 512. 16 dsts per block.
__global__ __launch_bounds__(512, 4)
void agg1_kernel(const float* __restrict__ h1, const float* __restrict__ a_src,
                 const float* __restrict__ a_dst, const float* __restrict__ b1,
                 float* __restrict__ hrelu) {
    __shared__ float s_as[NN];
    __shared__ float s_ad[16];
    __shared__ float sp[16][NN];
    __shared__ float s_den[16];

    const int b = blockIdx.z, head = blockIdx.y, d0 = blockIdx.x * 16;
    const int t = threadIdx.x;

    if (t < NN) s_as[t] = a_src[(b * NN + t) * H1 + head];
    if (t < 16) s_ad[t] = a_dst[(b * NN + d0 + t) * H1 + head];
    __syncthreads();

    // softmax: 32 threads per dst, 8 srcs each; width-32 shuffle reductions.
    const int d = t >> 5, l = t & 31;
    const float adst = s_ad[d];
    float e[8];
    float mx = -1e30f;
    #pragma unroll
    for (int i = 0; i < 8; ++i) {
        float v = lrelu(s_as[l + i * 32] + adst);
        e[i] = v;
        mx = fmaxf(mx, v);
    }
    #pragma unroll
    for (int off = 16; off > 0; off >>= 1)
        mx = fmaxf(mx, __shfl_down(mx, off, 32));
    mx = __shfl(mx, 0, 32);
    float sum = 0.f;
    #pragma unroll
    for (int i = 0; i < 8; ++i) {
        float p = __expf(e[i] - mx);
        sp[d][l + i * 32] = p;
        sum += p;
    }
    #pragma unroll
    for (int off = 16; off > 0; off >>= 1)
        sum += __shfl_down(sum, off, 32);
    if (l == 0) s_den[d] = sum + 1e-16f;
    __syncthreads();

    // aggregation: 4 groups x 128 cols; each thread 4 dsts.
    const int c = t & 127, g = t >> 7;
    float c0 = 0.f, c1 = 0.f, c2 = 0.f, c3 = 0.f;
    const float* hb = h1 + (size_t)(b * NN) * HC1 + head * C1 + c;
    #pragma unroll 4
    for (int src = 0; src < NN; ++src) {
        float hv = hb[(size_t)src * HC1];
        c0 = fmaf(sp[g * 4 + 0][src], hv, c0);
        c1 = fmaf(sp[g * 4 + 1][src], hv, c1);
        c2 = fmaf(sp[g * 4 + 2][src], hv, c2);
        c3 = fmaf(sp[g * 4 + 3][src], hv, c3);
    }
    float accs[4] = {c0, c1, c2, c3};
    const float bias = b1[head * C1 + c];
    #pragma unroll
    for (int j = 0; j < 4; ++j) {
        int dst = d0 + g * 4 + j;
        float v = accs[j] / s_den[g * 4 + j] + bias;
        hrelu[(b * NN + dst) * HC1 + head * C1 + c] = fmaxf(v, 0.f);
    }
}

// ---------------- K3: h2 = hrelu @ W2, fused a_src2/a_dst2 ------------------
// grid (64, 8), block 512. Block: 4 rows x 128 cols (full cols -> full a-reduce).
__global__ __launch_bounds__(512, 4)
void gemm2_fused(const float* __restrict__ hrelu, const float* __restrict__ W2,
                 const float* __restrict__ as2, const float* __restrict__ ad2,
                 float* __restrict__ h2, float* __restrict__ a_src,
                 float* __restrict__ a_dst) {
    __shared__ float xs[4][HC1];            // 8 KB
    __shared__ float redS[4][2], redD[4][2];
    const int b = blockIdx.y, r0 = blockIdx.x * 4, t = threadIdx.x;

    const float4* xp = (const float4*)(hrelu + (size_t)(b * NN + r0) * HC1);
    ((float4*)xs)[t] = xp[t];               // 4x512 floats = 512 float4
    __syncthreads();

    const int c = t & 127, rg = t >> 7;     // 128 threads (2 waves) per row
    float acc = 0.f;
    #pragma unroll 8
    for (int k = 0; k < HC1; ++k)
        acc = fmaf(xs[rg][k], W2[k * FIN + c], acc);
    h2[(b * NN + r0 + rg) * FIN + c] = acc;

    float s = acc * as2[c], d = acc * ad2[c];
    const int lane = t & 63, w = (t >> 6) & 1;
    #pragma unroll
    for (int off = 32; off > 0; off >>= 1) {
        s += __shfl_down(s, off, 64);
        d += __shfl_down(d, off, 64);
    }
    if (lane == 0) { redS[rg][w] = s; redD[rg][w] = d; }
    __syncthreads();
    if (t < 4) {
        a_src[b * NN + r0 + t] = redS[t][0] + redS[t][1];
        a_dst[b * NN + r0 + t] = redD[t][0] + redD[t][1];
    }
}

// ---------------- K4: layer-2 softmax + aggregate + bias --------------------
// grid (64, 8), block 512. 4 dsts per block (128 threads = 2 waves each).
__global__ __launch_bounds__(512, 4)
void agg2_kernel(const float* __restrict__ h2, const float* __restrict__ a_src,
                 const float* __restrict__ a_dst, const float* __restrict__ b2,
                 float* __restrict__ out) {
    __shared__ float s_as[NN];
    __shared__ float s_ad[4];
    __shared__ float sp[4][NN];
    __shared__ float redm[4][2], reds[4][2];

    const int b = blockIdx.y, d0 = blockIdx.x * 4, t = threadIdx.x;

    if (t < NN) s_as[t] = a_src[b * NN + t];
    if (t < 4) s_ad[t] = a_dst[b * NN + d0 + t];
    __syncthreads();

    const int d = t >> 7, l = t & 127, lane = t & 63, w = (t >> 6) & 1;
    const float adst = s_ad[d];
    float e0 = lrelu(s_as[l] + adst);
    float e1 = lrelu(s_as[l + 128] + adst);
    float mx = fmaxf(e0, e1);
    #pragma unroll
    for (int off = 32; off > 0; off >>= 1)
        mx = fmaxf(mx, __shfl_down(mx, off, 64));
    if (lane == 0) redm[d][w] = mx;
    __syncthreads();
    const float m = fmaxf(redm[d][0], redm[d][1]);
    float p0 = __expf(e0 - m), p1 = __expf(e1 - m);
    sp[d][l] = p0;
    sp[d][l + 128] = p1;
    float sum = p0 + p1;
    #pragma unroll
    for (int off = 32; off > 0; off >>= 1)
        sum += __shfl_down(sum, off, 64);
    if (lane == 0) reds[d][w] = sum;
    __syncthreads();
    const float den = reds[d][0] + reds[d][1] + 1e-16f;

    float acc = 0.f;
    const float* hb = h2 + (size_t)(b * NN) * FIN + l;
    #pragma unroll 4
    for (int src = 0; src < NN; ++src)
        acc = fmaf(sp[d][src], hb[(size_t)src * FIN], acc);
    out[(b * NN + d0 + d) * FIN + l] = acc / den + b2[l];
}

// ---------------- launch -----------------------------------------------------
extern "C" void kernel_launch(void* const* d_in, const int* in_sizes, int n_in,
                              void* d_out, int out_size, void* d_ws, size_t ws_size,
                              hipStream_t stream) {
    const float* x   = (const float*)d_in[0];
    const float* W1  = (const float*)d_in[1];
    const float* as1 = (const float*)d_in[2];
    const float* ad1 = (const float*)d_in[3];
    const float* b1  = (const float*)d_in[4];
    const float* W2  = (const float*)d_in[5];
    const float* as2 = (const float*)d_in[6];
    const float* ad2 = (const float*)d_in[7];
    const float* b2  = (const float*)d_in[8];
    float* out = (float*)d_out;

    float* ws = (float*)d_ws;
    float* h1     = ws;                      // 8*256*512 = 1048576
    float* hrelu  = ws + 1048576;            // 1048576
    float* h2     = ws + 2097152;            // 262144
    float* a_src1 = ws + 2359296;            // 8192
    float* a_dst1 = ws + 2367488;            // 8192
    float* a_src2 = ws + 2375680;            // 2048
    float* a_dst2 = ws + 2377728;            // 2048

    gemm1_fused<<<dim3(64, BATCH), 512, 0, stream>>>(x, W1, as1, ad1, h1, a_src1, a_dst1);
    agg1_kernel<<<dim3(16, H1, BATCH), 512, 0, stream>>>(h1, a_src1, a_dst1, b1, hrelu);
    gemm2_fused<<<dim3(64, BATCH), 512, 0, stream>>>(hrelu, W2, as2, ad2, h2, a_src2, a_dst2);
    agg2_kernel<<<dim3(64, BATCH), 512, 0, stream>>>(h2, a_src2, a_dst2, b2, out);
}

// Round 6
// 122.724 us; speedup vs baseline: 1.1940x; 1.1940x over previous
//
#include <hip/hip_runtime.h>
#include <hip/hip_bf16.h>

#define BATCH 8
#define NN    256
#define FIN   128
#define H1    4
#define C1    128
#define HC1   512   // H1*C1
#define NEG_SLOPE 0.2f

__device__ __forceinline__ float lrelu(float v) {
    return v > 0.f ? v : NEG_SLOPE * v;
}

// ---------------- K1: h1 = x @ W1, fused a_src1/a_dst1 ----------------------
// grid (64, 8), block 512. Block: 4 rows x 512 cols. 4 FMA per W1 load.
__global__ __launch_bounds__(512, 4)
void gemm1_fused(const float* __restrict__ x, const float* __restrict__ W1,
                 const float* __restrict__ as1, const float* __restrict__ ad1,
                 float* __restrict__ h1, float* __restrict__ a_src,
                 float* __restrict__ a_dst) {
    __shared__ float xs[4][FIN];
    __shared__ float redS[4][8], redD[4][8];
    const int b = blockIdx.y, r0 = blockIdx.x * 4, t = threadIdx.x;

    if (t < 128)   // 4 rows x 128 = 128 float4, coalesced
        ((float4*)xs)[t] = ((const float4*)(x + (size_t)(b * NN + r0) * FIN))[t];
    __syncthreads();

    float a0 = 0.f, a1 = 0.f, a2 = 0.f, a3 = 0.f;
    #pragma unroll 8
    for (int k = 0; k < FIN; ++k) {
        float w = W1[k * HC1 + t];
        a0 = fmaf(xs[0][k], w, a0);
        a1 = fmaf(xs[1][k], w, a1);
        a2 = fmaf(xs[2][k], w, a2);
        a3 = fmaf(xs[3][k], w, a3);
    }
    float acc[4] = {a0, a1, a2, a3};
    #pragma unroll
    for (int r = 0; r < 4; ++r)
        h1[(b * NN + r0 + r) * HC1 + t] = acc[r];

    // fused a-reductions: col t -> head t>>7; att vectors are flat [512].
    const float as = as1[t], ad = ad1[t];
    const int w = t >> 6, lane = t & 63;
    #pragma unroll
    for (int r = 0; r < 4; ++r) {
        float s = acc[r] * as, d = acc[r] * ad;
        #pragma unroll
        for (int off = 32; off > 0; off >>= 1) {
            s += __shfl_down(s, off, 64);
            d += __shfl_down(d, off, 64);
        }
        if (lane == 0) { redS[r][w] = s; redD[r][w] = d; }
    }
    __syncthreads();
    if (t < 16) {   // wave w covers cols [64w,64w+63] -> head w>>1
        int r = t & 3, h = t >> 2;
        a_src[(b * NN + r0 + r) * H1 + h] = redS[r][2 * h] + redS[r][2 * h + 1];
        a_dst[(b * NN + r0 + r) * H1 + h] = redD[r][2 * h] + redD[r][2 * h + 1];
    }
}

// ---------------- K2: layer-1 softmax + aggregate + bias + relu -------------
// grid (16 dst-tiles, 4 heads, 8 batch), block 512. 16 dsts/block, 4 FMA/load.
__global__ __launch_bounds__(512, 4)
void agg1_kernel(const float* __restrict__ h1, const float* __restrict__ a_src,
                 const float* __restrict__ a_dst, const float* __restrict__ b1,
                 float* __restrict__ hrelu) {
    __shared__ float s_as[NN];
    __shared__ float s_ad[16];
    __shared__ float sp[16][NN];
    __shared__ float s_den[16];

    const int b = blockIdx.z, head = blockIdx.y, d0 = blockIdx.x * 16;
    const int t = threadIdx.x;

    if (t < NN) s_as[t] = a_src[(b * NN + t) * H1 + head];
    if (t < 16) s_ad[t] = a_dst[(b * NN + d0 + t) * H1 + head];
    __syncthreads();

    // softmax: 32 threads per dst, 8 srcs each; width-32 shuffle reductions.
    const int d = t >> 5, l = t & 31;
    const float adst = s_ad[d];
    float e[8];
    float mx = -1e30f;
    #pragma unroll
    for (int i = 0; i < 8; ++i) {
        float v = lrelu(s_as[l + i * 32] + adst);
        e[i] = v;
        mx = fmaxf(mx, v);
    }
    #pragma unroll
    for (int off = 16; off > 0; off >>= 1)
        mx = fmaxf(mx, __shfl_down(mx, off, 32));
    mx = __shfl(mx, 0, 32);
    float sum = 0.f;
    #pragma unroll
    for (int i = 0; i < 8; ++i) {
        float p = __expf(e[i] - mx);
        sp[d][l + i * 32] = p;
        sum += p;
    }
    #pragma unroll
    for (int off = 16; off > 0; off >>= 1)
        sum += __shfl_down(sum, off, 32);
    if (l == 0) s_den[d] = sum + 1e-16f;
    __syncthreads();

    // aggregation: 4 groups x 128 cols; each thread 4 dsts -> 4 FMA per load.
    const int c = t & 127, g = t >> 7;
    float c0 = 0.f, c1 = 0.f, c2 = 0.f, c3 = 0.f;
    const float* hb = h1 + (size_t)(b * NN) * HC1 + head * C1 + c;
    #pragma unroll 4
    for (int src = 0; src < NN; ++src) {
        float hv = hb[(size_t)src * HC1];
        c0 = fmaf(sp[g * 4 + 0][src], hv, c0);
        c1 = fmaf(sp[g * 4 + 1][src], hv, c1);
        c2 = fmaf(sp[g * 4 + 2][src], hv, c2);
        c3 = fmaf(sp[g * 4 + 3][src], hv, c3);
    }
    float accs[4] = {c0, c1, c2, c3};
    const float bias = b1[head * C1 + c];
    #pragma unroll
    for (int j = 0; j < 4; ++j) {
        int dst = d0 + g * 4 + j;
        float v = accs[j] / s_den[g * 4 + j] + bias;
        hrelu[(b * NN + dst) * HC1 + head * C1 + c] = fmaxf(v, 0.f);
    }
}

// ---------------- K3: h2 = hrelu @ W2, fused a_src2/a_dst2 ------------------
// grid (64, 8), block 512. 4 rows/block; K split 4-way (g = k-chunk).
// Each thread: 128 k-iters x (1 load + 4 FMA); LDS reduction across chunks.
__global__ __launch_bounds__(512, 4)
void gemm2_fused(const float* __restrict__ hrelu, const float* __restrict__ W2,
                 const float* __restrict__ as2, const float* __restrict__ ad2,
                 float* __restrict__ h2, float* __restrict__ a_src,
                 float* __restrict__ a_dst) {
    __shared__ float xs[4][HC1];            // 8 KB
    __shared__ float red[3][4][FIN];        // 6 KB
    __shared__ float redS[4][2], redD[4][2];
    const int b = blockIdx.y, r0 = blockIdx.x * 4, t = threadIdx.x;

    ((float4*)xs)[t] = ((const float4*)(hrelu + (size_t)(b * NN + r0) * HC1))[t];
    __syncthreads();

    const int c = t & 127, g = t >> 7;      // g = K-chunk [g*128, g*128+128)
    float acc[4] = {0.f, 0.f, 0.f, 0.f};
    const int k0 = g * 128;
    #pragma unroll 8
    for (int kk = 0; kk < 128; ++kk) {
        int k = k0 + kk;
        float w = W2[k * FIN + c];
        acc[0] = fmaf(xs[0][k], w, acc[0]);
        acc[1] = fmaf(xs[1][k], w, acc[1]);
        acc[2] = fmaf(xs[2][k], w, acc[2]);
        acc[3] = fmaf(xs[3][k], w, acc[3]);
    }
    if (g > 0) {
        #pragma unroll
        for (int r = 0; r < 4; ++r) red[g - 1][r][c] = acc[r];
    }
    __syncthreads();
    if (g == 0) {
        #pragma unroll
        for (int r = 0; r < 4; ++r) {
            acc[r] += red[0][r][c] + red[1][r][c] + red[2][r][c];
            h2[(b * NN + r0 + r) * FIN + c] = acc[r];
        }
        // a-reduce over c: 128 threads = 2 waves
        const int lane = t & 63, w2 = t >> 6;
        const float as = as2[c], ad = ad2[c];
        #pragma unroll
        for (int r = 0; r < 4; ++r) {
            float s = acc[r] * as, d = acc[r] * ad;
            #pragma unroll
            for (int off = 32; off > 0; off >>= 1) {
                s += __shfl_down(s, off, 64);
                d += __shfl_down(d, off, 64);
            }
            if (lane == 0) { redS[r][w2] = s; redD[r][w2] = d; }
        }
    }
    __syncthreads();
    if (t < 4) {
        a_src[b * NN + r0 + t] = redS[t][0] + redS[t][1];
        a_dst[b * NN + r0 + t] = redD[t][0] + redD[t][1];
    }
}

// ---------------- K4: layer-2 softmax + aggregate + bias --------------------
// grid (64, 8), block 512. 4 dsts/block; agg splits srcs 4-way (q), 4 FMA/load.
__global__ __launch_bounds__(512, 4)
void agg2_kernel(const float* __restrict__ h2, const float* __restrict__ a_src,
                 const float* __restrict__ a_dst, const float* __restrict__ b2,
                 float* __restrict__ out) {
    __shared__ float s_as[NN];
    __shared__ float s_ad[4];
    __shared__ float sp[4][NN];
    __shared__ float redm[4][2], reds[4][2];
    __shared__ float s_den[4];
    __shared__ float redA[3][4][FIN];       // 6 KB

    const int b = blockIdx.y, d0 = blockIdx.x * 4, t = threadIdx.x;

    if (t < NN) s_as[t] = a_src[b * NN + t];
    if (t < 4) s_ad[t] = a_dst[b * NN + d0 + t];
    __syncthreads();

    // softmax: 128-thread group per dst.
    const int d = t >> 7, l = t & 127, lane = t & 63, w = (t >> 6) & 1;
    const float adst = s_ad[d];
    float e0 = lrelu(s_as[l] + adst);
    float e1 = lrelu(s_as[l + 128] + adst);
    float mx = fmaxf(e0, e1);
    #pragma unroll
    for (int off = 32; off > 0; off >>= 1)
        mx = fmaxf(mx, __shfl_down(mx, off, 64));
    if (lane == 0) redm[d][w] = mx;
    __syncthreads();
    const float m = fmaxf(redm[d][0], redm[d][1]);
    float p0 = __expf(e0 - m), p1 = __expf(e1 - m);
    sp[d][l] = p0;
    sp[d][l + 128] = p1;
    float sum = p0 + p1;
    #pragma unroll
    for (int off = 32; off > 0; off >>= 1)
        sum += __shfl_down(sum, off, 64);
    if (lane == 0) reds[d][w] = sum;
    __syncthreads();
    if (t < 4) s_den[t] = reds[t][0] + reds[t][1] + 1e-16f;
    __syncthreads();

    // aggregation: q = src-quarter; all 4 dsts per thread -> 4 FMA per load.
    const int c = l, q = d;
    float a4[4] = {0.f, 0.f, 0.f, 0.f};
    const float* hb = h2 + ((size_t)(b * NN) + q * 64) * FIN + c;
    #pragma unroll 8
    for (int i = 0; i < 64; ++i) {
        float hv = hb[(size_t)i * FIN];
        int src = q * 64 + i;
        a4[0] = fmaf(sp[0][src], hv, a4[0]);
        a4[1] = fmaf(sp[1][src], hv, a4[1]);
        a4[2] = fmaf(sp[2][src], hv, a4[2]);
        a4[3] = fmaf(sp[3][src], hv, a4[3]);
    }
    if (q > 0) {
        #pragma unroll
        for (int j = 0; j < 4; ++j) redA[q - 1][j][c] = a4[j];
    }
    __syncthreads();
    if (q == 0) {
        #pragma unroll
        for (int j = 0; j < 4; ++j) {
            float v = a4[j] + redA[0][j][c] + redA[1][j][c] + redA[2][j][c];
            out[(b * NN + d0 + j) * FIN + c] = v / s_den[j] + b2[c];
        }
    }
}

// ---------------- launch -----------------------------------------------------
extern "C" void kernel_launch(void* const* d_in, const int* in_sizes, int n_in,
                              void* d_out, int out_size, void* d_ws, size_t ws_size,
                              hipStream_t stream) {
    const float* x   = (const float*)d_in[0];
    const float* W1  = (const float*)d_in[1];
    const float* as1 = (const float*)d_in[2];
    const float* ad1 = (const float*)d_in[3];
    const float* b1  = (const float*)d_in[4];
    const float* W2  = (const float*)d_in[5];
    const float* as2 = (const float*)d_in[6];
    const float* ad2 = (const float*)d_in[7];
    const float* b2  = (const float*)d_in[8];
    float* out = (float*)d_out;

    float* ws = (float*)d_ws;
    float* h1     = ws;                      // 8*256*512 = 1048576
    float* hrelu  = ws + 1048576;            // 1048576
    float* h2     = ws + 2097152;            // 262144
    float* a_src1 = ws + 2359296;            // 8192
    float* a_dst1 = ws + 2367488;            // 8192
    float* a_src2 = ws + 2375680;            // 2048
    float* a_dst2 = ws + 2377728;            // 2048

    gemm1_fused<<<dim3(64, BATCH), 512, 0, stream>>>(x, W1, as1, ad1, h1, a_src1, a_dst1);
    agg1_kernel<<<dim3(16, H1, BATCH), 512, 0, stream>>>(h1, a_src1, a_dst1, b1, hrelu);
    gemm2_fused<<<dim3(64, BATCH), 512, 0, stream>>>(hrelu, W2, as2, ad2, h2, a_src2, a_dst2);
    agg2_kernel<<<dim3(64, BATCH), 512, 0, stream>>>(h2, a_src2, a_dst2, b2, out);
}